// Round 4
// baseline (125.423 us; speedup 1.0000x reference)
//
#include <hip/hip_runtime.h>

typedef unsigned short u16;
typedef unsigned int u32;
typedef __attribute__((ext_vector_type(8))) __bf16 bf16x8;
typedef __attribute__((ext_vector_type(4))) float f32x4;
typedef __attribute__((ext_vector_type(4))) u32 u32x4;
typedef __attribute__((ext_vector_type(4))) u16 u16x4;

#define DEV __device__ __forceinline__

constexpr int S_LEN = 2048;
constexpr int DMODEL = 1024;
constexpr int NHEAD = 16;
constexpr int EX = 3072;     // 3*D
constexpr int ROWS = 4096;   // B*S
// fold 1/sqrt(64) * log2(e) into Q so softmax is exp2(s - B), B = 16
constexpr float QSCALE = 0.125f * 1.4426950408889634f;

DEV u16 f2bf(float f) {
  union { float f; u32 u; } v; v.f = f;
  u32 u = v.u;
  u32 r = (u + 0x7fffu + ((u >> 16) & 1u)) >> 16;  // RNE
  return (u16)r;
}
DEV float bf2f(u32 lo16) {
  union { u32 u; float f; } v; v.u = lo16 << 16; return v.f;
}
DEV float vexp2(float x) {
#if __has_builtin(__builtin_amdgcn_exp2f)
  return __builtin_amdgcn_exp2f(x);
#else
  return exp2f(x);
#endif
}
// async global->LDS, 16B per lane (m97 recipe)
DEV void gload_lds16(const u16* g, u16* l) {
  __builtin_amdgcn_global_load_lds((const __attribute__((address_space(1))) void*)g,
                                   (__attribute__((address_space(3))) void*)l, 16, 0, 0);
}
// XOR swizzle for [rows][64] u16 LDS tiles (row stride 128B), 8-col granules
DEV int swz(int r, int c) { return r * 64 + (c ^ ((r & 7) << 3)); }

// ---------------- fused fp32 -> bf16 convert for x, w_qkv, w_out ----------------
__global__ __launch_bounds__(256) void k_cvt_all(const float* __restrict__ x,
                                                 const float* __restrict__ wq,
                                                 const float* __restrict__ wo,
                                                 u16* __restrict__ xb,
                                                 u16* __restrict__ wqb,
                                                 u16* __restrict__ wob) {
  int i = blockIdx.x * 256 + threadIdx.x;  // 1048576 total (x8 elems)
  const float* in; u16* out; int off;
  if (i < 524288)       { in = x;  out = xb;  off = i; }
  else if (i < 917504)  { in = wq; out = wqb; off = i - 524288; }
  else                  { in = wo; out = wob; off = i - 917504; }
  const float4* p4 = (const float4*)in;
  float4 a = p4[2 * off], b = p4[2 * off + 1];
  alignas(16) u16 r[8] = {f2bf(a.x), f2bf(a.y), f2bf(a.z), f2bf(a.w),
                          f2bf(b.x), f2bf(b.y), f2bf(b.z), f2bf(b.w)};
  *(u32x4*)(out + 8 * off) = *(const u32x4*)r;
}

// ---------------- RoPE cos/sin tables: [S][32] ----------------
__global__ __launch_bounds__(256) void k_rope_tab(const int* __restrict__ pos,
                                                  float* __restrict__ ctab,
                                                  float* __restrict__ stab) {
  int t = blockIdx.x * 256 + threadIdx.x;  // S*32 = 65536
  int s = t >> 5, fi = t & 31;
  float p = (float)pos[s];
  float invf = expf(-(float)fi * 0.28782313662425572f);  // 10000^(-fi/32)
  float ang = p * invf;
  ctab[t] = cosf(ang);
  stab[t] = sinf(ang);
}

// ---------------- in-place RoPE on qk buffer [ROWS][2048] (bf16) ----------------
// q third (p==0) additionally scaled by QSCALE for exp2-softmax
__global__ __launch_bounds__(256) void k_rope(u16* __restrict__ qk,
                                              const float* __restrict__ ctab,
                                              const float* __restrict__ stab) {
  int idx = blockIdx.x * 256 + threadIdx.x;  // ROWS * 1024 pair-slots
  int row = idx >> 10, rem = idx & 1023;
  int p = rem >> 9, hfi = rem & 511;
  int h = hfi >> 5, fi = hfi & 31;
  int s = row & (S_LEN - 1);
  u32* ptr = (u32*)(qk + (size_t)row * 2048 + p * 1024 + h * 64 + 2 * fi);
  u32 v = *ptr;
  float xe = bf2f(v & 0xffffu), xo = bf2f(v >> 16);
  float c = ctab[s * 32 + fi], sn = stab[s * 32 + fi];
  float scl = (p == 0) ? QSCALE : 1.0f;
  u32 lo = (u32)f2bf((xe * c - xo * sn) * scl);
  u32 hi = (u32)f2bf((xe * sn + xo * c) * scl);
  *ptr = lo | (hi << 16);
}

// ================= GEMM1: 256x256 8-phase template (T3+T4+T5) =================
// C[m][n] = sum_k A[m][k]*B[n][k], M=4096 N=3072 K=1024, BK=64, 512 thr = 8 waves
// (2M x 4N). Epilogue: cols<2048 -> qk bf16 [row][2048]; else V^T -> vt.
// LDS: [2 buf][2 half][128][64] for A and B = 128 KiB. Conflict-free involution
// swizzle g' = g ^ (row&7) applied on pre-swizzled GLOBAL source + ds_read side.
__global__ __launch_bounds__(512, 2) void k_gemm1_8ph(const u16* __restrict__ A,
                                                      const u16* __restrict__ Bw,
                                                      u16* __restrict__ qk,
                                                      u16* __restrict__ vt) {
  __shared__ alignas(16) u16 Asm[2][2][8192];
  __shared__ alignas(16) u16 Bsm[2][2][8192];
  const int tid = threadIdx.x;
  const int lane = tid & 63, l15 = lane & 15, l16 = lane >> 4;
  const int w = tid >> 6, wr = w >> 2, wc = w & 3;
  const int m0 = blockIdx.x * 256, n0 = blockIdx.y * 256;

  // staging: thread tid covers LDS granule tid*16B (+ round*8KB) of a half-tile.
  // slot (row sr, granule g) holds global granule g^(sr&7)  [involution]
  const int sr = tid >> 3, gg = tid & 7;
  const int swcol = ((gg ^ (sr & 7)) * 8);
  const u16* aS = A + (size_t)(m0 + sr) * 1024 + swcol;
  const u16* bS = Bw + (size_t)(n0 + sr) * 1024 + swcol;
  const int ldst = tid * 8;  // u16 idx within half; + round*4096

#define STAGE_A(T, h) do { \
    const u16* s_ = aS + (size_t)((h) * 128) * 1024 + (T) * 64; \
    u16* d_ = &Asm[(T) & 1][(h)][ldst]; \
    gload_lds16(s_, d_); \
    gload_lds16(s_ + 64 * 1024, d_ + 4096); \
  } while (0)
#define STAGE_B(T, h) do { \
    const u16* s_ = bS + (size_t)((h) * 128) * 1024 + (T) * 64; \
    u16* d_ = &Bsm[(T) & 1][(h)][ldst]; \
    gload_lds16(s_, d_); \
    gload_lds16(s_ + 64 * 1024, d_ + 4096); \
  } while (0)

  // ds_read offsets: row rl, granule (kk*4+l16) ^ (rl&7); rl&7 == l15&7
  const int xr = l15 & 7;
  const int offK0 = l15 * 64 + ((l16 ^ xr) * 8);
  const int offK1 = l15 * 64 + (((4 + l16) ^ xr) * 8);
  const int brow = (wc & 1) * 64;

  f32x4 acc[8][4] = {};

  // prologue: T0 fully + T1.A  (12 vm-ops; entry vmcnt(4) leaves T1.A in flight)
  STAGE_A(0, 0); STAGE_A(0, 1);
  STAGE_B(0, 0); STAGE_B(0, 1);
  STAGE_A(1, 0); STAGE_A(1, 1);

#define PHASE_SYNC() do { \
    asm volatile("s_waitcnt lgkmcnt(0)" ::: "memory"); \
    asm volatile("s_barrier" ::: "memory"); \
    __builtin_amdgcn_sched_barrier(0); \
  } while (0)
#define MFMA16(mh, nh) do { \
    __builtin_amdgcn_s_setprio(1); \
    _Pragma("unroll") \
    for (int m_ = 0; m_ < 4; m_++) \
      _Pragma("unroll") \
      for (int j_ = 0; j_ < 2; j_++) \
        _Pragma("unroll") \
        for (int k_ = 0; k_ < 2; k_++) \
          acc[(mh) * 4 + m_][(nh) * 2 + j_] = __builtin_amdgcn_mfma_f32_16x16x32_bf16( \
              Ar[mh][m_][k_], Br[j_][k_], acc[(mh) * 4 + m_][(nh) * 2 + j_], 0, 0, 0); \
    __builtin_amdgcn_s_setprio(0); \
    asm volatile("s_barrier" ::: "memory"); \
    __builtin_amdgcn_sched_barrier(0); \
  } while (0)

  for (int T = 0; T < 16; ++T) {
    if (T < 15) asm volatile("s_waitcnt vmcnt(4)" ::: "memory");
    else        asm volatile("s_waitcnt vmcnt(0)" ::: "memory");
    asm volatile("s_barrier" ::: "memory");
    __builtin_amdgcn_sched_barrier(0);
    const u16* Ab = &Asm[T & 1][wr][0];
    const u16* Bb = &Bsm[T & 1][wc >> 1][0];
    bf16x8 Ar[2][4][2], Br[2][2];

    // phase 0: read A[mh0] + B[nh0]; stage (T+1).B0; mfma Q(0,0)
#pragma unroll
    for (int m = 0; m < 4; m++) {
      Ar[0][m][0] = *(const bf16x8*)&Ab[(m * 16) * 64 + offK0];
      Ar[0][m][1] = *(const bf16x8*)&Ab[(m * 16) * 64 + offK1];
    }
#pragma unroll
    for (int j = 0; j < 2; j++) {
      Br[j][0] = *(const bf16x8*)&Bb[(brow + j * 16) * 64 + offK0];
      Br[j][1] = *(const bf16x8*)&Bb[(brow + j * 16) * 64 + offK1];
    }
    if (T + 1 < 16) STAGE_B(T + 1, 0);
    PHASE_SYNC();
    MFMA16(0, 0);

    // phase 1: read A[mh1]; stage (T+1).B1; mfma Q(1,0)
#pragma unroll
    for (int m = 0; m < 4; m++) {
      Ar[1][m][0] = *(const bf16x8*)&Ab[(64 + m * 16) * 64 + offK0];
      Ar[1][m][1] = *(const bf16x8*)&Ab[(64 + m * 16) * 64 + offK1];
    }
    if (T + 1 < 16) STAGE_B(T + 1, 1);
    PHASE_SYNC();
    MFMA16(1, 0);

    // phase 2: read B[nh1]; stage (T+2).A0; mfma Q(0,1)
#pragma unroll
    for (int j = 0; j < 2; j++) {
      Br[j][0] = *(const bf16x8*)&Bb[(brow + 32 + j * 16) * 64 + offK0];
      Br[j][1] = *(const bf16x8*)&Bb[(brow + 32 + j * 16) * 64 + offK1];
    }
    if (T + 2 < 16) STAGE_A(T + 2, 0);
    PHASE_SYNC();
    MFMA16(0, 1);

    // phase 3: stage (T+2).A1; mfma Q(1,1)
    if (T + 2 < 16) STAGE_A(T + 2, 1);
    PHASE_SYNC();
    MFMA16(1, 1);
  }

  // epilogue: C/D layout col = l15, row = l16*4 + reg
  const int rb = m0 + wr * 128 + l16 * 4;
  const int cb = n0 + wc * 64 + l15;
  if (n0 < 2048) {
#pragma unroll
    for (int m = 0; m < 8; m++)
#pragma unroll
      for (int n = 0; n < 4; n++)
#pragma unroll
        for (int r = 0; r < 4; r++) {
          int row = rb + m * 16 + r, col = cb + n * 16;
          qk[(size_t)row * 2048 + col] = f2bf(acc[m][n][r]);
        }
  } else {
#pragma unroll
    for (int m = 0; m < 8; m++)
#pragma unroll
      for (int n = 0; n < 4; n++) {
        int row = rb + m * 16, col = cb + n * 16;
        int bb = row >> 11, s = row & 2047, hd = col - 2048;
        u16x4 pk = {f2bf(acc[m][n][0]), f2bf(acc[m][n][1]),
                    f2bf(acc[m][n][2]), f2bf(acc[m][n][3])};
        *(u16x4*)&vt[(size_t)(bb * 1024 + hd) * 2048 + s] = pk;
      }
  }
#undef STAGE_A
#undef STAGE_B
#undef PHASE_SYNC
#undef MFMA16
}

// ---------------- GEMM (128^2, 2-phase) — used for the output projection ----
template <int MODE>
__global__ __launch_bounds__(256) void k_gemm_bt(const u16* __restrict__ A,
                                                 const u16* __restrict__ Bw,
                                                 void* __restrict__ Out,
                                                 u16* __restrict__ vt,
                                                 int M, int N, int K) {
  __shared__ alignas(16) u16 As[128 * 32];
  __shared__ alignas(16) u16 Bs[128 * 32];
  const int tid = threadIdx.x, lane = tid & 63;
  const int w = tid >> 6, wr = w >> 1, wc = w & 1;
  const int l15 = lane & 15, l16 = lane >> 4;
  const int m0 = blockIdx.x * 128, n0 = blockIdx.y * 128;
  f32x4 acc[4][4] = {};
  const int grow = w * 32 + (lane >> 2);      // + i*16
  const int gcol = (lane & 3) * 8;
  const int ldst = w * 1024 + lane * 8;       // u16 index; + i*512

  for (int k0 = 0; k0 < K; k0 += 32) {
    __syncthreads();
#pragma unroll
    for (int i = 0; i < 2; i++) {
      gload_lds16(&A[(size_t)(m0 + grow + i * 16) * K + k0 + gcol], &As[ldst + i * 512]);
      gload_lds16(&Bw[(size_t)(n0 + grow + i * 16) * K + k0 + gcol], &Bs[ldst + i * 512]);
    }
    __syncthreads();
    bf16x8 af[4], bfr[4];
#pragma unroll
    for (int m = 0; m < 4; m++) af[m] = *(const bf16x8*)&As[(wr * 64 + m * 16 + l15) * 32 + l16 * 8];
#pragma unroll
    for (int n = 0; n < 4; n++) bfr[n] = *(const bf16x8*)&Bs[(wc * 64 + n * 16 + l15) * 32 + l16 * 8];
#pragma unroll
    for (int m = 0; m < 4; m++)
#pragma unroll
      for (int n = 0; n < 4; n++)
        acc[m][n] = __builtin_amdgcn_mfma_f32_16x16x32_bf16(af[m], bfr[n], acc[m][n], 0, 0, 0);
  }

  const int rb = m0 + wr * 64 + l16 * 4;
  const int cb = n0 + wc * 64 + l15;
#pragma unroll
  for (int m = 0; m < 4; m++)
#pragma unroll
    for (int n = 0; n < 4; n++)
#pragma unroll
      for (int r = 0; r < 4; r++) {
        int row = rb + m * 16 + r, col = cb + n * 16;
        if (MODE == 1)
          ((u16*)Out)[(size_t)row * 2048 + col] = f2bf(acc[m][n][r]);
        else
          ((float*)Out)[(size_t)row * N + col] = acc[m][n][r];
      }
}

// ---------------- causal flash attention, fixed-max exp2 softmax ----------------
__global__ __launch_bounds__(256) void k_attn(const u16* __restrict__ qk,
                                              const u16* __restrict__ vt,
                                              u16* __restrict__ aout) {
  __shared__ alignas(16) u16 Ks[64 * 64];     // K tile [kv][d], swizzled
  __shared__ alignas(16) u16 Vs[64 * 64];     // V^T tile [d][kv], swizzled
  __shared__ alignas(16) u16 Ps[4][16 * 64];  // per-wave P [q][kv], swizzled
  const int tid = threadIdx.x, lane = tid & 63, w = tid >> 6;
  const int l15 = lane & 15, l16 = lane >> 4;
  const int qt = 31 - blockIdx.y;
  const int q0 = qt * 64;
  const int bh = blockIdx.x, b = bh >> 4, h = bh & 15;
  const u16* qbase = qk + (size_t)b * S_LEN * 2048 + h * 64;
  const u16* kbase = qbase + 1024;
  const u16* vbase = vt + (size_t)bh * 64 * S_LEN;
  const int wq0 = q0 + w * 16;

  bf16x8 qa[2];
#pragma unroll
  for (int kb = 0; kb < 2; kb++)
    qa[kb] = *(const bf16x8*)&qbase[(size_t)(wq0 + l15) * 2048 + kb * 32 + l16 * 8];

  bf16x8 vone;
#pragma unroll
  for (int j = 0; j < 8; j++) vone[j] = (__bf16)1.0f;

  f32x4 osum[4] = {};
  f32x4 osl = {};  // row-sum of P (all 16 cols identical)

  const int nt = qt + 1;  // 64-wide kv tiles
  const int srow = tid >> 2, scg = (tid & 3) * 16;
  u32x4 kr0, kr1, vr0, vr1;
  {
    const u16* kp = kbase + (size_t)srow * 2048 + scg;
    kr0 = *(const u32x4*)kp; kr1 = *(const u32x4*)(kp + 8);
    const u16* vp = vbase + (size_t)srow * S_LEN + scg;
    vr0 = *(const u32x4*)vp; vr1 = *(const u32x4*)(vp + 8);
  }

  for (int t = 0; t < nt; t++) {
    const int kv0 = t * 64;
    __syncthreads();  // everyone done reading previous tile
    *(u32x4*)&Ks[swz(srow, scg)]     = kr0;
    *(u32x4*)&Ks[swz(srow, scg + 8)] = kr1;
    *(u32x4*)&Vs[swz(srow, scg)]     = vr0;
    *(u32x4*)&Vs[swz(srow, scg + 8)] = vr1;
    __syncthreads();  // tile ready
    if (t + 1 < nt) {  // register prefetch of next tile drains under compute
      const u16* kp = kbase + (size_t)(kv0 + 64 + srow) * 2048 + scg;
      kr0 = *(const u32x4*)kp; kr1 = *(const u32x4*)(kp + 8);
      const u16* vp = vbase + (size_t)srow * S_LEN + kv0 + 64 + scg;
      vr0 = *(const u32x4*)vp; vr1 = *(const u32x4*)(vp + 8);
    }

    // QK^T: 16 q rows x 64 kv per wave (Q pre-scaled by QSCALE)
    f32x4 sc[4];
#pragma unroll
    for (int n = 0; n < 4; n++) {
      bf16x8 kf0 = *(const bf16x8*)&Ks[swz(n * 16 + l15, l16 * 8)];
      bf16x8 kf1 = *(const bf16x8*)&Ks[swz(n * 16 + l15, 32 + l16 * 8)];
      f32x4 z = {0.f, 0.f, 0.f, 0.f};
      z = __builtin_amdgcn_mfma_f32_16x16x32_bf16(qa[0], kf0, z, 0, 0, 0);
      sc[n] = __builtin_amdgcn_mfma_f32_16x16x32_bf16(qa[1], kf1, z, 0, 0, 0);
    }

    // P = exp2(s - 16); causal mask only on the diagonal tile
    const bool diag = (t == nt - 1);
#pragma unroll
    for (int n = 0; n < 4; n++)
#pragma unroll
      for (int r = 0; r < 4; r++) {
        float s = sc[n][r];
        if (diag && (kv0 + n * 16 + l15 > wq0 + l16 * 4 + r)) s = -1e30f;
        float p = vexp2(s - 16.0f);
        Ps[w][swz(l16 * 4 + r, n * 16 + l15)] = f2bf(p);
      }

    // PV + row-sum: A = P (16q x 64kv), B^T = V^T. Same-wave LDS, no barrier.
#pragma unroll
    for (int ks = 0; ks < 2; ks++) {
      bf16x8 pa = *(const bf16x8*)&Ps[w][swz(l15, ks * 32 + l16 * 8)];
      osl = __builtin_amdgcn_mfma_f32_16x16x32_bf16(pa, vone, osl, 0, 0, 0);
#pragma unroll
      for (int n = 0; n < 4; n++) {
        bf16x8 vb = *(const bf16x8*)&Vs[swz(n * 16 + l15, ks * 32 + l16 * 8)];
        osum[n] = __builtin_amdgcn_mfma_f32_16x16x32_bf16(pa, vb, osum[n], 0, 0, 0);
      }
    }
  }

  f32x4 inv;
#pragma unroll
  for (int r = 0; r < 4; r++) inv[r] = 1.0f / osl[r];
  u16* ob = aout + (size_t)b * S_LEN * DMODEL + h * 64;
#pragma unroll
  for (int n = 0; n < 4; n++)
#pragma unroll
    for (int r = 0; r < 4; r++) {
      int s = wq0 + l16 * 4 + r;
      ob[(size_t)s * DMODEL + n * 16 + l15] = f2bf(osum[n][r] * inv[r]);
    }
}

extern "C" void kernel_launch(void* const* d_in, const int* in_sizes, int n_in,
                              void* d_out, int out_size, void* d_ws, size_t ws_size,
                              hipStream_t stream) {
  const float* x = (const float*)d_in[0];
  const int* pos = (const int*)d_in[1];
  const float* wqkv = (const float*)d_in[2];
  const float* wout = (const float*)d_in[3];
  float* out = (float*)d_out;
  char* ws = (char*)d_ws;

  // workspace layout (bytes) — ~50.9 MB total
  u16* qkb  = (u16*)(ws);                       // [4096][2048] q,k  16,777,216
  u16* vtb  = (u16*)(ws + 16777216);            // [2][16][64][2048]  8,388,608
  u16* aoutb = (u16*)(ws + 25165824);           // [4096][1024]       8,388,608
  u16* xb   = (u16*)(ws + 33554432);            //                    8,388,608
  u16* wqb  = (u16*)(ws + 41943040);            //                    6,291,456
  u16* wob  = (u16*)(ws + 48234496);            //                    2,097,152
  float* ctab = (float*)(ws + 50331648);        //                      262,144
  float* stab = (float*)(ws + 50593792);        //                      262,144
  (void)ws_size;

  k_cvt_all<<<4096, 256, 0, stream>>>(x, wqkv, wout, xb, wqb, wob);
  k_rope_tab<<<65536 / 256, 256, 0, stream>>>(pos, ctab, stab);

  dim3 g1(ROWS / 256, EX / 256);  // 16 x 12 = 192 blocks
  k_gemm1_8ph<<<g1, 512, 0, stream>>>(xb, wqb, qkb, vtb);

  k_rope<<<(ROWS * 1024) / 256, 256, 0, stream>>>(qkb, ctab, stab);

  dim3 ga(2 * NHEAD, S_LEN / 64);  // x = bh (fast, XCD spread), y = qtile slot
  k_attn<<<ga, 256, 0, stream>>>(qkb, vtb, aoutb);

  dim3 g2(ROWS / 128, DMODEL / 128);  // 32 x 8
  k_gemm_bt<0><<<g2, 256, 0, stream>>>(aoutb, wob, out, nullptr, ROWS, DMODEL, DMODEL);
}

// Round 5
// 103.831 us; speedup vs baseline: 1.2079x; 1.2079x over previous
//
#include <hip/hip_runtime.h>

typedef unsigned short u16;
typedef unsigned int u32;
typedef __attribute__((ext_vector_type(8))) __bf16 bf16x8;
typedef __attribute__((ext_vector_type(4))) float f32x4;
typedef __attribute__((ext_vector_type(4))) u32 u32x4;
typedef __attribute__((ext_vector_type(4))) u16 u16x4;

#define DEV __device__ __forceinline__

constexpr int S_LEN = 2048;
constexpr int DMODEL = 1024;
constexpr int NHEAD = 16;
constexpr int ROWS = 4096;   // B*S
// fold 1/sqrt(64) * log2(e) into Q so softmax is exp2(s - B), B = 16
constexpr float QSCALE = 0.125f * 1.4426950408889634f;

DEV u16 f2bf(float f) {
  union { float f; u32 u; } v; v.f = f;
  u32 u = v.u;
  u32 r = (u + 0x7fffu + ((u >> 16) & 1u)) >> 16;  // RNE
  return (u16)r;
}
DEV float vexp2(float x) {
#if __has_builtin(__builtin_amdgcn_exp2f)
  return __builtin_amdgcn_exp2f(x);
#else
  return exp2f(x);
#endif
}
// async global->LDS, 16B per lane (m97 recipe)
DEV void gload_lds16(const u16* g, u16* l) {
  __builtin_amdgcn_global_load_lds((const __attribute__((address_space(1))) void*)g,
                                   (__attribute__((address_space(3))) void*)l, 16, 0, 0);
}
// XOR swizzle for [rows][64] u16 LDS tiles (row stride 128B), 8-col granules
DEV int swz(int r, int c) { return r * 64 + (c ^ ((r & 7) << 3)); }

// ---------------- fused fp32 -> bf16 convert for x, w_qkv, w_out ----------------
__global__ __launch_bounds__(256) void k_cvt_all(const float* __restrict__ x,
                                                 const float* __restrict__ wq,
                                                 const float* __restrict__ wo,
                                                 u16* __restrict__ xb,
                                                 u16* __restrict__ wqb,
                                                 u16* __restrict__ wob) {
  int i = blockIdx.x * 256 + threadIdx.x;  // 1048576 total (x8 elems)
  const float* in; u16* out; int off;
  if (i < 524288)       { in = x;  out = xb;  off = i; }
  else if (i < 917504)  { in = wq; out = wqb; off = i - 524288; }
  else                  { in = wo; out = wob; off = i - 917504; }
  const float4* p4 = (const float4*)in;
  float4 a = p4[2 * off], b = p4[2 * off + 1];
  alignas(16) u16 r[8] = {f2bf(a.x), f2bf(a.y), f2bf(a.z), f2bf(a.w),
                          f2bf(b.x), f2bf(b.y), f2bf(b.z), f2bf(b.w)};
  *(u32x4*)(out + 8 * off) = *(const u32x4*)r;
}

// ---------------- RoPE cos/sin table: [S][32] float2 (cos, sin) ----------------
__global__ __launch_bounds__(256) void k_rope_tab(const int* __restrict__ pos,
                                                  float2* __restrict__ tab) {
  int t = blockIdx.x * 256 + threadIdx.x;  // S*32 = 65536
  int s = t >> 5, fi = t & 31;
  float p = (float)pos[s];
  float invf = expf(-(float)fi * 0.28782313662425572f);  // 10000^(-fi/32)
  float ang = p * invf;
  tab[t] = float2{cosf(ang), sinf(ang)};
}

// ================= GEMM template: 128x128, BK=64, 4 waves, dbuf, T3-min ========
// C[m][n] = sum_k A[m][k]*B[n][k], K=1024 (16 tiles). 2 blocks/CU (64 KiB LDS).
// MODE 1 (QKV): cols<2048 -> RoPE(+QSCALE on q) fused -> bf16 qk[row][2048];
//               cols>=2048 -> V^T bf16 vt[(b*1024+hd)][s].
// MODE 0: fp32 out [M][1024].
template <int MODE>
__global__ __launch_bounds__(256, 2) void k_gemm(const u16* __restrict__ A,
                                                 const u16* __restrict__ Bw,
                                                 void* __restrict__ Out,
                                                 u16* __restrict__ vt,
                                                 const float2* __restrict__ tab,
                                                 int NB) {
  __shared__ alignas(16) u16 As[2][8192];  // [buf][128][64] swizzled
  __shared__ alignas(16) u16 Bs[2][8192];
  const int tid = threadIdx.x, lane = tid & 63;
  const int w = tid >> 6, wr = w >> 1, wc = w & 1;
  const int l15 = lane & 15, l16 = lane >> 4;
  // bijective XCD swizzle (grid multiple of 8)
  const int cpx = gridDim.x >> 3;
  const int wg = (blockIdx.x & 7) * cpx + (blockIdx.x >> 3);
  const int mb = wg / NB, nb = wg - mb * NB;
  const int m0 = mb * 128, n0 = nb * 128;

  // staging: 256 threads cover [128][64] in 4 chunks; involution granule swizzle
  const int sr = tid >> 3;
  const int swcol = ((tid & 7) ^ (sr & 7)) * 8;
  const u16* aT = A + (size_t)(m0 + sr) * 1024 + swcol;
  const u16* bT = Bw + (size_t)(n0 + sr) * 1024 + swcol;
  const int dst0 = tid * 8;

#define STAGE(bufc, t) do { \
    _Pragma("unroll") \
    for (int i_ = 0; i_ < 4; i_++) { \
      gload_lds16(aT + (size_t)(i_ * 32) * 1024 + (t) * 64, &As[bufc][dst0 + i_ * 2048]); \
      gload_lds16(bT + (size_t)(i_ * 32) * 1024 + (t) * 64, &Bs[bufc][dst0 + i_ * 2048]); \
    } \
  } while (0)

  f32x4 acc[4][4] = {};
  const int x7 = l15 & 7;

#define COMPUTE(bufc) do { \
    bf16x8 af_[4][2], bf_[4][2]; \
    _Pragma("unroll") \
    for (int m_ = 0; m_ < 4; m_++) \
      _Pragma("unroll") \
      for (int k_ = 0; k_ < 2; k_++) \
        af_[m_][k_] = *(const bf16x8*)&As[bufc][(wr * 64 + m_ * 16 + l15) * 64 + \
                                               (((k_ * 4 + l16) ^ x7) * 8)]; \
    _Pragma("unroll") \
    for (int n_ = 0; n_ < 4; n_++) \
      _Pragma("unroll") \
      for (int k_ = 0; k_ < 2; k_++) \
        bf_[n_][k_] = *(const bf16x8*)&Bs[bufc][(wc * 64 + n_ * 16 + l15) * 64 + \
                                               (((k_ * 4 + l16) ^ x7) * 8)]; \
    __builtin_amdgcn_s_setprio(1); \
    _Pragma("unroll") \
    for (int m_ = 0; m_ < 4; m_++) \
      _Pragma("unroll") \
      for (int n_ = 0; n_ < 4; n_++) \
        _Pragma("unroll") \
        for (int k_ = 0; k_ < 2; k_++) \
          acc[m_][n_] = __builtin_amdgcn_mfma_f32_16x16x32_bf16( \
              af_[m_][k_], bf_[n_][k_], acc[m_][n_], 0, 0, 0); \
    __builtin_amdgcn_s_setprio(0); \
  } while (0)

#define VMBAR() do { \
    asm volatile("s_waitcnt vmcnt(0)" ::: "memory"); \
    asm volatile("s_barrier" ::: "memory"); \
  } while (0)

  STAGE(0, 0);
  VMBAR();
  for (int t = 0; t < 16; t += 2) {
    STAGE(1, t + 1);          // flies under COMPUTE(0)'s MFMAs
    COMPUTE(0);
    VMBAR();
    if (t + 2 < 16) {
      STAGE(0, t + 2);
      COMPUTE(1);
      VMBAR();
    } else {
      COMPUTE(1);
    }
  }
#undef STAGE
#undef COMPUTE
#undef VMBAR

  // epilogue — C/D layout (m89/m91): col = lane&15, row = (lane>>4)*4 + reg
  const int rb = m0 + wr * 64 + l16 * 4;
  const int cb = n0 + wc * 64 + l15;
  if (MODE == 0) {
    float* o = (float*)Out;
#pragma unroll
    for (int m = 0; m < 4; m++)
#pragma unroll
      for (int n = 0; n < 4; n++)
#pragma unroll
        for (int r = 0; r < 4; r++)
          o[(size_t)(rb + m * 16 + r) * 1024 + cb + n * 16] = acc[m][n][r];
  } else if (n0 >= 2048) {
    // V third -> vt[(b*1024 + hd)][s], 4 consecutive s per lane packed as 8B
#pragma unroll
    for (int m = 0; m < 4; m++)
#pragma unroll
      for (int n = 0; n < 4; n++) {
        int row = rb + m * 16, col = cb + n * 16;
        int bb = row >> 11, s = row & 2047, hd = col - 2048;
        u16x4 pk = {f2bf(acc[m][n][0]), f2bf(acc[m][n][1]),
                    f2bf(acc[m][n][2]), f2bf(acc[m][n][3])};
        *(u16x4*)&vt[(size_t)(bb * 1024 + hd) * S_LEN + s] = pk;
      }
  } else {
    // q,k thirds: fused RoPE (+QSCALE on q). Pair (even,odd) cols live in
    // adjacent lanes -> one shfl_xor(1) exchanges partners.
    u16* qk = (u16*)Out;
    const bool isq = (n0 < 1024);
#pragma unroll
    for (int m = 0; m < 4; m++) {
      int row0 = rb + m * 16;
      int s0 = row0 & 2047;
#pragma unroll
      for (int n = 0; n < 4; n++) {
        int col = cb + n * 16;
        int fi = (col & 63) >> 1;
        bool odd = col & 1;
        f32x4 v = acc[m][n];
        f32x4 p;
#pragma unroll
        for (int r = 0; r < 4; r++) p[r] = __shfl_xor(v[r], 1);
#pragma unroll
        for (int r = 0; r < 4; r++) {
          float2 cs = tab[(s0 + r) * 32 + fi];
          float xe = odd ? p[r] : v[r];
          float xo = odd ? v[r] : p[r];
          float o = odd ? (xe * cs.y + xo * cs.x) : (xe * cs.x - xo * cs.y);
          if (isq) o *= QSCALE;
          qk[(size_t)(row0 + r) * 2048 + col] = f2bf(o);
        }
      }
    }
  }
}

// ---------------- causal flash attention, fixed-max exp2 softmax ----------------
// grid: (bh=32, j=32), qt = 31-j (LPT). 4 waves, wave w owns q rows
// [q0+16w, +16). KVBLK=64. lsum via MFMA-with-ones.
__global__ __launch_bounds__(256) void k_attn(const u16* __restrict__ qk,
                                              const u16* __restrict__ vt,
                                              u16* __restrict__ aout) {
  __shared__ alignas(16) u16 Ks[64 * 64];     // K tile [kv][d], swizzled
  __shared__ alignas(16) u16 Vs[64 * 64];     // V^T tile [d][kv], swizzled
  __shared__ alignas(16) u16 Ps[4][16 * 64];  // per-wave P [q][kv], swizzled
  const int tid = threadIdx.x, lane = tid & 63, w = tid >> 6;
  const int l15 = lane & 15, l16 = lane >> 4;
  const int qt = 31 - blockIdx.y;
  const int q0 = qt * 64;
  const int bh = blockIdx.x, b = bh >> 4, h = bh & 15;
  const u16* qbase = qk + (size_t)b * S_LEN * 2048 + h * 64;
  const u16* kbase = qbase + 1024;
  const u16* vbase = vt + (size_t)bh * 64 * S_LEN;
  const int wq0 = q0 + w * 16;

  bf16x8 qa[2];
#pragma unroll
  for (int kb = 0; kb < 2; kb++)
    qa[kb] = *(const bf16x8*)&qbase[(size_t)(wq0 + l15) * 2048 + kb * 32 + l16 * 8];

  bf16x8 vone;
#pragma unroll
  for (int j = 0; j < 8; j++) vone[j] = (__bf16)1.0f;

  f32x4 osum[4] = {};
  f32x4 osl = {};  // row-sum of P (all 16 cols identical)

  const int nt = qt + 1;  // 64-wide kv tiles
  const int srow = tid >> 2, scg = (tid & 3) * 16;
  u32x4 kr0, kr1, vr0, vr1;
  {
    const u16* kp = kbase + (size_t)srow * 2048 + scg;
    kr0 = *(const u32x4*)kp; kr1 = *(const u32x4*)(kp + 8);
    const u16* vp = vbase + (size_t)srow * S_LEN + scg;
    vr0 = *(const u32x4*)vp; vr1 = *(const u32x4*)(vp + 8);
  }

  for (int t = 0; t < nt; t++) {
    const int kv0 = t * 64;
    __syncthreads();  // everyone done reading previous tile
    *(u32x4*)&Ks[swz(srow, scg)]     = kr0;
    *(u32x4*)&Ks[swz(srow, scg + 8)] = kr1;
    *(u32x4*)&Vs[swz(srow, scg)]     = vr0;
    *(u32x4*)&Vs[swz(srow, scg + 8)] = vr1;
    __syncthreads();  // tile ready
    if (t + 1 < nt) {  // register prefetch of next tile drains under compute
      const u16* kp = kbase + (size_t)(kv0 + 64 + srow) * 2048 + scg;
      kr0 = *(const u32x4*)kp; kr1 = *(const u32x4*)(kp + 8);
      const u16* vp = vbase + (size_t)srow * S_LEN + kv0 + 64 + scg;
      vr0 = *(const u32x4*)vp; vr1 = *(const u32x4*)(vp + 8);
    }

    // QK^T: 16 q rows x 64 kv per wave (Q pre-scaled by QSCALE)
    f32x4 sc[4];
#pragma unroll
    for (int n = 0; n < 4; n++) {
      bf16x8 kf0 = *(const bf16x8*)&Ks[swz(n * 16 + l15, l16 * 8)];
      bf16x8 kf1 = *(const bf16x8*)&Ks[swz(n * 16 + l15, 32 + l16 * 8)];
      f32x4 z = {0.f, 0.f, 0.f, 0.f};
      z = __builtin_amdgcn_mfma_f32_16x16x32_bf16(qa[0], kf0, z, 0, 0, 0);
      sc[n] = __builtin_amdgcn_mfma_f32_16x16x32_bf16(qa[1], kf1, z, 0, 0, 0);
    }

    // P = exp2(s - 16); causal mask only on the diagonal tile
    const bool diag = (t == nt - 1);
#pragma unroll
    for (int n = 0; n < 4; n++)
#pragma unroll
      for (int r = 0; r < 4; r++) {
        float s = sc[n][r];
        if (diag && (kv0 + n * 16 + l15 > wq0 + l16 * 4 + r)) s = -1e30f;
        float p = vexp2(s - 16.0f);
        Ps[w][swz(l16 * 4 + r, n * 16 + l15)] = f2bf(p);
      }

    // PV + row-sum: A = P (16q x 64kv), B^T = V^T. Same-wave LDS, no barrier.
#pragma unroll
    for (int ks = 0; ks < 2; ks++) {
      bf16x8 pa = *(const bf16x8*)&Ps[w][swz(l15, ks * 32 + l16 * 8)];
      osl = __builtin_amdgcn_mfma_f32_16x16x32_bf16(pa, vone, osl, 0, 0, 0);
#pragma unroll
      for (int n = 0; n < 4; n++) {
        bf16x8 vb = *(const bf16x8*)&Vs[swz(n * 16 + l15, ks * 32 + l16 * 8)];
        osum[n] = __builtin_amdgcn_mfma_f32_16x16x32_bf16(pa, vb, osum[n], 0, 0, 0);
      }
    }
  }

  f32x4 inv;
#pragma unroll
  for (int r = 0; r < 4; r++) inv[r] = 1.0f / osl[r];
  u16* ob = aout + (size_t)b * S_LEN * DMODEL + h * 64;
#pragma unroll
  for (int n = 0; n < 4; n++)
#pragma unroll
    for (int r = 0; r < 4; r++) {
      int s = wq0 + l16 * 4 + r;
      ob[(size_t)s * DMODEL + n * 16 + l15] = f2bf(osum[n][r] * inv[r]);
    }
}

extern "C" void kernel_launch(void* const* d_in, const int* in_sizes, int n_in,
                              void* d_out, int out_size, void* d_ws, size_t ws_size,
                              hipStream_t stream) {
  const float* x = (const float*)d_in[0];
  const int* pos = (const int*)d_in[1];
  const float* wqkv = (const float*)d_in[2];
  const float* wout = (const float*)d_in[3];
  float* out = (float*)d_out;
  char* ws = (char*)d_ws;

  // workspace layout (bytes) — ~50.9 MB total
  u16* qkb   = (u16*)(ws);                      // [4096][2048] q,k  16,777,216
  u16* vtb   = (u16*)(ws + 16777216);           // [2][16][64][2048]  8,388,608
  u16* aoutb = (u16*)(ws + 25165824);           // [4096][1024]       8,388,608
  u16* xb    = (u16*)(ws + 33554432);           //                    8,388,608
  u16* wqb   = (u16*)(ws + 41943040);           //                    6,291,456
  u16* wob   = (u16*)(ws + 48234496);           //                    2,097,152
  float2* tab = (float2*)(ws + 50331648);       // 2048*32*8   =      524,288
  (void)ws_size;

  k_cvt_all<<<4096, 256, 0, stream>>>(x, wqkv, wout, xb, wqb, wob);
  k_rope_tab<<<65536 / 256, 256, 0, stream>>>(pos, tab);

  // GEMM1: 32 x 24 = 768 blocks (exactly 3 dispatch rounds), RoPE fused
  k_gemm<1><<<768, 256, 0, stream>>>(xb, wqb, qkb, vtb, tab, 24);

  dim3 ga(2 * NHEAD, S_LEN / 64);  // x = bh (fast, XCD spread), y = qtile slot
  k_attn<<<ga, 256, 0, stream>>>(qkb, vtb, aoutb);

  // GEMM2: 32 x 8 = 256 blocks (exactly 1 round)
  k_gemm<0><<<256, 256, 0, stream>>>(aoutb, wob, out, nullptr, nullptr, 8);
}